// Round 1
// baseline (826.295 us; speedup 1.0000x reference)
//
#include <hip/hip_runtime.h>
#include <cmath>

// DeepSeek MoE layer, MI355X (gfx950).
// B=2,S=1024 -> T=2048 tokens. H=1024, FF=4096, E=64, K=8, M=512.
// out  = fp32 [2048*1024] then logits fp32 [2048*64], concatenated in d_out.
//
// Design (round 0, correctness-first):
//  - router logits in fp32 (top-k selection must match numpy ref; a selection
//    swap costs ~0.04 absmax which is near threshold 8.8e-2)
//  - all big GEMMs in fp16 MFMA (16x16x32_f16), fp32 accumulate.
//    fp16 chosen over bf16: 8x lower rounding error, same MFMA rate.
//  - routed (top-8) expert compute only: 69 GF instead of reference's 275 GF.
//  - fp32->fp16 conversion happens during LDS staging (no extra HBM pass).

typedef _Float16 f16;
typedef __attribute__((ext_vector_type(4))) _Float16 f16x4;
typedef __attribute__((ext_vector_type(8))) _Float16 f16x8;
typedef __attribute__((ext_vector_type(4))) float f32x4;

#define NT 2048      // tokens
#define HD 1024      // hidden
#define FF 4096      // shared intermediate
#define NE 64        // experts
#define TOPK 8
#define MD 512       // moe intermediate

// ---- workspace layout (bytes) ----
#define H1_OFF      0ull                            // fp16 [2048][4096]  16 MB
#define HEXP_OFF    16777216ull                     // fp16 [16448][512]  16 MB (64 pad rows)
#define TOPKI_OFF   (HEXP_OFF + 16842752ull)        // int  [2048*8]
#define TOPKW_OFF   (TOPKI_OFF + 65536ull)          // f32  [2048*8]
#define COUNTS_OFF  (TOPKW_OFF + 65536ull)          // int  [64]
#define CURSORS_OFF (COUNTS_OFF + 256ull)           // int  [64]
#define OFFSETS_OFF (CURSORS_OFF + 256ull)          // int  [64]
#define RTOK_OFF    (OFFSETS_OFF + 256ull)          // int  [16384]
#define RW_OFF      (RTOK_OFF + 65536ull)           // f32  [16384]

// ------------------------------------------------------------------
// router: logits[t][e] = dot(x[t], Wg[:,e]) in fp32. 4 tokens / block.
__global__ __launch_bounds__(256) void k_router(const float* __restrict__ X,
                                                const float* __restrict__ Wg,
                                                float* __restrict__ logits)
{
    __shared__ float xs[4][HD];
    const int tid = threadIdx.x;
    const int t0 = blockIdx.x * 4;
    #pragma unroll
    for (int i = 0; i < 4; ++i) {
        int f4 = tid + i * 256;            // 1024 float4 total
        int row = f4 >> 8;                 // 256 float4 per row
        int col = (f4 & 255) * 4;
        *(float4*)&xs[row][col] = *(const float4*)&X[(t0 + row) * HD + col];
    }
    __syncthreads();
    const int e = tid & 63, tok = tid >> 6;
    float a0 = 0.f, a1 = 0.f, a2 = 0.f, a3 = 0.f;
    const float* xr = xs[tok];
    for (int h = 0; h < HD; h += 4) {
        a0 += xr[h + 0] * Wg[(h + 0) * NE + e];
        a1 += xr[h + 1] * Wg[(h + 1) * NE + e];
        a2 += xr[h + 2] * Wg[(h + 2) * NE + e];
        a3 += xr[h + 3] * Wg[(h + 3) * NE + e];
    }
    logits[(t0 + tok) * NE + e] = (a0 + a1) + (a2 + a3);
}

// ------------------------------------------------------------------
// top-8 + softmax per token; one wave per token. Tie-break: lower index
// (matches jax.lax.top_k).
__global__ __launch_bounds__(64) void k_topk(const float* __restrict__ logits,
                                             int* __restrict__ topk_idx,
                                             float* __restrict__ topk_w,
                                             int* __restrict__ counts)
{
    const int t = blockIdx.x;
    const int lane = threadIdx.x;
    __shared__ float sval[TOPK];
    __shared__ int sidx[TOPK];
    float cur = logits[t * NE + lane];
    for (int it = 0; it < TOPK; ++it) {
        float v = cur; int id = lane;
        #pragma unroll
        for (int off = 32; off > 0; off >>= 1) {
            float ov = __shfl_xor(v, off, 64);
            int   oi = __shfl_xor(id, off, 64);
            if (ov > v || (ov == v && oi < id)) { v = ov; id = oi; }
        }
        if (lane == 0) { sval[it] = v; sidx[it] = id; }
        if (lane == id) cur = -INFINITY;
    }
    __syncthreads();
    if (lane < TOPK) {
        float m = sval[0];
        float denom = 0.f;
        #pragma unroll
        for (int j = 0; j < TOPK; ++j) denom += expf(sval[j] - m);
        float w = expf(sval[lane] - m) / denom;
        int e = sidx[lane];
        topk_idx[t * TOPK + lane] = e;
        topk_w[t * TOPK + lane] = w;
        atomicAdd(&counts[e], 1);
    }
}

// exclusive scan of 64 counts (tiny, single thread)
__global__ void k_scan(const int* __restrict__ counts, int* __restrict__ offsets)
{
    if (threadIdx.x == 0) {
        int run = 0;
        for (int e = 0; e < NE; ++e) { offsets[e] = run; run += counts[e]; }
    }
}

// scatter (t, weight) into per-expert packed slots
__global__ __launch_bounds__(256) void k_route(const int* __restrict__ topk_idx,
                                               const float* __restrict__ topk_w,
                                               const int* __restrict__ offsets,
                                               int* __restrict__ cursors,
                                               int* __restrict__ rtok,
                                               float* __restrict__ rw)
{
    int i = blockIdx.x * 256 + threadIdx.x;   // < 16384
    int e = topk_idx[i];
    int pos = atomicAdd(&cursors[e], 1);
    int slot = offsets[e] + pos;
    rtok[slot] = i >> 3;
    rw[slot] = topk_w[i];
}

// ------------------------------------------------------------------
// GEMM tiling: BM=BN=64, BK=32, 256 threads = 4 waves (2x2 of 32x32).
// LDS: As[64][40] fp16 (row m, k contiguous), Bs[64][40] fp16 (row n, k contiguous).
// MFMA fragment mapping (guide §3, m89/m120 verified):
//   A[m=lane&15][k=(lane>>4)*8+j], B[k=(lane>>4)*8+j][n=lane&15],
//   C/D: col=lane&15, row=(lane>>4)*4+reg.

// shared expert GEMM1: H1 = silu(X @ Ws1), fp16 out. M=2048,N=4096,K=1024
__global__ __launch_bounds__(256) void k_shared1(const float* __restrict__ X,
                                                 const float* __restrict__ W,
                                                 f16* __restrict__ H1)
{
    __shared__ alignas(16) f16 As[64][40];
    __shared__ alignas(16) f16 Bs[64][40];
    const int tid = threadIdx.x;
    const int n0 = blockIdx.x * 64, m0 = blockIdx.y * 64;
    const int lane = tid & 63, wave = tid >> 6;
    const int wm = (wave >> 1) * 32, wn = (wave & 1) * 32;
    const int fr = lane & 15, q = lane >> 4;

    f32x4 acc[2][2];
    #pragma unroll
    for (int i = 0; i < 2; ++i)
        #pragma unroll
        for (int j = 0; j < 2; ++j) acc[i][j] = (f32x4){0.f, 0.f, 0.f, 0.f};

    for (int kt = 0; kt < HD; kt += 32) {
        #pragma unroll
        for (int i = 0; i < 2; ++i) {            // A: 64x32 f32 -> f16
            int f = tid + i * 256;
            int r = f >> 3, c = (f & 7) * 4;
            float4 v = *(const float4*)&X[(m0 + r) * HD + kt + c];
            f16x4 h = { (f16)v.x, (f16)v.y, (f16)v.z, (f16)v.w };
            *(f16x4*)&As[r][c] = h;
        }
        #pragma unroll
        for (int i = 0; i < 8; ++i) {            // B: 32x64 f32, transpose -> [n][k]
            int g = tid + i * 256;
            int k = g >> 6, n = g & 63;
            Bs[n][k] = (f16)W[(kt + k) * FF + n0 + n];
        }
        __syncthreads();
        f16x8 a0 = *(const f16x8*)&As[wm + fr][q * 8];
        f16x8 a1 = *(const f16x8*)&As[wm + 16 + fr][q * 8];
        f16x8 b0 = *(const f16x8*)&Bs[wn + fr][q * 8];
        f16x8 b1 = *(const f16x8*)&Bs[wn + 16 + fr][q * 8];
        acc[0][0] = __builtin_amdgcn_mfma_f32_16x16x32_f16(a0, b0, acc[0][0], 0, 0, 0);
        acc[0][1] = __builtin_amdgcn_mfma_f32_16x16x32_f16(a0, b1, acc[0][1], 0, 0, 0);
        acc[1][0] = __builtin_amdgcn_mfma_f32_16x16x32_f16(a1, b0, acc[1][0], 0, 0, 0);
        acc[1][1] = __builtin_amdgcn_mfma_f32_16x16x32_f16(a1, b1, acc[1][1], 0, 0, 0);
        __syncthreads();
    }
    #pragma unroll
    for (int i = 0; i < 2; ++i)
        #pragma unroll
        for (int j = 0; j < 2; ++j)
            #pragma unroll
            for (int r = 0; r < 4; ++r) {
                int m = m0 + wm + i * 16 + q * 4 + r;
                int n = n0 + wn + j * 16 + fr;
                float v = acc[i][j][r];
                float s = v / (1.f + expf(-v));
                H1[m * FF + n] = (f16)s;
            }
}

// shared expert GEMM2: Out = H1 @ Ws2 (fp32 plain store). M=2048,N=1024,K=4096
__global__ __launch_bounds__(256) void k_shared2(const f16* __restrict__ H1,
                                                 const float* __restrict__ W,
                                                 float* __restrict__ Out)
{
    __shared__ alignas(16) f16 As[64][40];
    __shared__ alignas(16) f16 Bs[64][40];
    const int tid = threadIdx.x;
    const int n0 = blockIdx.x * 64, m0 = blockIdx.y * 64;
    const int lane = tid & 63, wave = tid >> 6;
    const int wm = (wave >> 1) * 32, wn = (wave & 1) * 32;
    const int fr = lane & 15, q = lane >> 4;

    f32x4 acc[2][2];
    #pragma unroll
    for (int i = 0; i < 2; ++i)
        #pragma unroll
        for (int j = 0; j < 2; ++j) acc[i][j] = (f32x4){0.f, 0.f, 0.f, 0.f};

    for (int kt = 0; kt < FF; kt += 32) {
        {                                        // A: 64x32 fp16, direct copy
            int r = tid >> 2, c = (tid & 3) * 8;
            f16x8 v = *(const f16x8*)&H1[(m0 + r) * FF + kt + c];
            *(f16x8*)&As[r][c] = v;
        }
        #pragma unroll
        for (int i = 0; i < 8; ++i) {
            int g = tid + i * 256;
            int k = g >> 6, n = g & 63;
            Bs[n][k] = (f16)W[(kt + k) * HD + n0 + n];
        }
        __syncthreads();
        f16x8 a0 = *(const f16x8*)&As[wm + fr][q * 8];
        f16x8 a1 = *(const f16x8*)&As[wm + 16 + fr][q * 8];
        f16x8 b0 = *(const f16x8*)&Bs[wn + fr][q * 8];
        f16x8 b1 = *(const f16x8*)&Bs[wn + 16 + fr][q * 8];
        acc[0][0] = __builtin_amdgcn_mfma_f32_16x16x32_f16(a0, b0, acc[0][0], 0, 0, 0);
        acc[0][1] = __builtin_amdgcn_mfma_f32_16x16x32_f16(a0, b1, acc[0][1], 0, 0, 0);
        acc[1][0] = __builtin_amdgcn_mfma_f32_16x16x32_f16(a1, b0, acc[1][0], 0, 0, 0);
        acc[1][1] = __builtin_amdgcn_mfma_f32_16x16x32_f16(a1, b1, acc[1][1], 0, 0, 0);
        __syncthreads();
    }
    #pragma unroll
    for (int i = 0; i < 2; ++i)
        #pragma unroll
        for (int j = 0; j < 2; ++j)
            #pragma unroll
            for (int r = 0; r < 4; ++r) {
                int m = m0 + wm + i * 16 + q * 4 + r;
                int n = n0 + wn + j * 16 + fr;
                Out[m * HD + n] = acc[i][j][r];
            }
}

// expert GEMM1: Hx[slot] = silu(X[rtok[slot]] @ W1[e]), fp16. K=1024, N=512
__global__ __launch_bounds__(256) void k_exp1(const float* __restrict__ X,
                                              const float* __restrict__ W1,
                                              const int* __restrict__ counts,
                                              const int* __restrict__ offsets,
                                              const int* __restrict__ rtok,
                                              f16* __restrict__ Hx)
{
    const int e = blockIdx.z;
    const int cnt = counts[e];
    const int mt = blockIdx.y * 64;
    if (mt >= cnt) return;
    const int off = offsets[e];
    const int n0 = blockIdx.x * 64;
    const float* W = W1 + (size_t)e * HD * MD;

    __shared__ alignas(16) f16 As[64][40];
    __shared__ alignas(16) f16 Bs[64][40];
    const int tid = threadIdx.x;
    const int lane = tid & 63, wave = tid >> 6;
    const int wm = (wave >> 1) * 32, wn = (wave & 1) * 32;
    const int fr = lane & 15, q = lane >> 4;

    // hoist gather: this thread stages rows r_a and r_a+32
    const int r_a = tid >> 3;
    const int c = (tid & 7) * 4;
    const int mr_a = mt + r_a, mr_b = mt + r_a + 32;
    const bool va = mr_a < cnt, vb = mr_b < cnt;
    const float* xa = X + (va ? (size_t)rtok[off + mr_a] * HD : 0);
    const float* xb = X + (vb ? (size_t)rtok[off + mr_b] * HD : 0);

    f32x4 acc[2][2];
    #pragma unroll
    for (int i = 0; i < 2; ++i)
        #pragma unroll
        for (int j = 0; j < 2; ++j) acc[i][j] = (f32x4){0.f, 0.f, 0.f, 0.f};

    for (int kt = 0; kt < HD; kt += 32) {
        {
            float4 v = {0.f, 0.f, 0.f, 0.f};
            if (va) v = *(const float4*)&xa[kt + c];
            f16x4 h = { (f16)v.x, (f16)v.y, (f16)v.z, (f16)v.w };
            *(f16x4*)&As[r_a][c] = h;
            float4 u = {0.f, 0.f, 0.f, 0.f};
            if (vb) u = *(const float4*)&xb[kt + c];
            f16x4 h2 = { (f16)u.x, (f16)u.y, (f16)u.z, (f16)u.w };
            *(f16x4*)&As[r_a + 32][c] = h2;
        }
        #pragma unroll
        for (int i = 0; i < 8; ++i) {
            int g = tid + i * 256;
            int k = g >> 6, n = g & 63;
            Bs[n][k] = (f16)W[(kt + k) * MD + n0 + n];
        }
        __syncthreads();
        f16x8 a0 = *(const f16x8*)&As[wm + fr][q * 8];
        f16x8 a1 = *(const f16x8*)&As[wm + 16 + fr][q * 8];
        f16x8 b0 = *(const f16x8*)&Bs[wn + fr][q * 8];
        f16x8 b1 = *(const f16x8*)&Bs[wn + 16 + fr][q * 8];
        acc[0][0] = __builtin_amdgcn_mfma_f32_16x16x32_f16(a0, b0, acc[0][0], 0, 0, 0);
        acc[0][1] = __builtin_amdgcn_mfma_f32_16x16x32_f16(a0, b1, acc[0][1], 0, 0, 0);
        acc[1][0] = __builtin_amdgcn_mfma_f32_16x16x32_f16(a1, b0, acc[1][0], 0, 0, 0);
        acc[1][1] = __builtin_amdgcn_mfma_f32_16x16x32_f16(a1, b1, acc[1][1], 0, 0, 0);
        __syncthreads();
    }
    #pragma unroll
    for (int i = 0; i < 2; ++i)
        #pragma unroll
        for (int j = 0; j < 2; ++j)
            #pragma unroll
            for (int r = 0; r < 4; ++r) {
                int m_in = mt + wm + i * 16 + q * 4 + r;
                if (m_in < cnt) {
                    int n = n0 + wn + j * 16 + fr;
                    float v = acc[i][j][r];
                    float s = v / (1.f + expf(-v));
                    Hx[(size_t)(off + m_in) * MD + n] = (f16)s;
                }
            }
}

// expert GEMM2: Out[t] += w * (Hx @ W2[e]). K=512, N=1024, atomic scatter.
__global__ __launch_bounds__(256) void k_exp2(const f16* __restrict__ Hx,
                                              const float* __restrict__ W2,
                                              const int* __restrict__ counts,
                                              const int* __restrict__ offsets,
                                              const int* __restrict__ rtok,
                                              const float* __restrict__ rw,
                                              float* __restrict__ Out)
{
    const int e = blockIdx.z;
    const int cnt = counts[e];
    const int mt = blockIdx.y * 64;
    if (mt >= cnt) return;
    const int off = offsets[e];
    const int n0 = blockIdx.x * 64;
    const float* W = W2 + (size_t)e * MD * HD;

    __shared__ alignas(16) f16 As[64][40];
    __shared__ alignas(16) f16 Bs[64][40];
    const int tid = threadIdx.x;
    const int lane = tid & 63, wave = tid >> 6;
    const int wm = (wave >> 1) * 32, wn = (wave & 1) * 32;
    const int fr = lane & 15, q = lane >> 4;

    f32x4 acc[2][2];
    #pragma unroll
    for (int i = 0; i < 2; ++i)
        #pragma unroll
        for (int j = 0; j < 2; ++j) acc[i][j] = (f32x4){0.f, 0.f, 0.f, 0.f};

    for (int kt = 0; kt < MD; kt += 32) {
        {   // A: rows are packed slots; Hx has 64 pad rows so OOB reads are safe
            int r = tid >> 2, c = (tid & 3) * 8;
            f16x8 v = *(const f16x8*)&Hx[(size_t)(off + mt + r) * MD + kt + c];
            *(f16x8*)&As[r][c] = v;
        }
        #pragma unroll
        for (int i = 0; i < 8; ++i) {
            int g = tid + i * 256;
            int k = g >> 6, n = g & 63;
            Bs[n][k] = (f16)W[(kt + k) * HD + n0 + n];
        }
        __syncthreads();
        f16x8 a0 = *(const f16x8*)&As[wm + fr][q * 8];
        f16x8 a1 = *(const f16x8*)&As[wm + 16 + fr][q * 8];
        f16x8 b0 = *(const f16x8*)&Bs[wn + fr][q * 8];
        f16x8 b1 = *(const f16x8*)&Bs[wn + 16 + fr][q * 8];
        acc[0][0] = __builtin_amdgcn_mfma_f32_16x16x32_f16(a0, b0, acc[0][0], 0, 0, 0);
        acc[0][1] = __builtin_amdgcn_mfma_f32_16x16x32_f16(a0, b1, acc[0][1], 0, 0, 0);
        acc[1][0] = __builtin_amdgcn_mfma_f32_16x16x32_f16(a1, b0, acc[1][0], 0, 0, 0);
        acc[1][1] = __builtin_amdgcn_mfma_f32_16x16x32_f16(a1, b1, acc[1][1], 0, 0, 0);
        __syncthreads();
    }
    #pragma unroll
    for (int i = 0; i < 2; ++i)
        #pragma unroll
        for (int j = 0; j < 2; ++j)
            #pragma unroll
            for (int r = 0; r < 4; ++r) {
                int m_in = mt + wm + i * 16 + q * 4 + r;
                if (m_in < cnt) {
                    int slot = off + m_in;
                    int t = rtok[slot];
                    float w = rw[slot];
                    int n = n0 + wn + j * 16 + fr;
                    atomicAdd(&Out[(size_t)t * HD + n], w * acc[i][j][r]);
                }
            }
}

// ------------------------------------------------------------------
extern "C" void kernel_launch(void* const* d_in, const int* in_sizes, int n_in,
                              void* d_out, int out_size, void* d_ws, size_t ws_size,
                              hipStream_t stream)
{
    (void)in_sizes; (void)n_in; (void)out_size; (void)ws_size;
    const float* X   = (const float*)d_in[0];
    const float* Ws1 = (const float*)d_in[1];
    const float* Ws2 = (const float*)d_in[2];
    const float* Wg  = (const float*)d_in[3];
    const float* W1  = (const float*)d_in[4];
    const float* W2  = (const float*)d_in[5];
    float* out = (float*)d_out;
    float* logits = out + (size_t)NT * HD;

    char* ws = (char*)d_ws;
    f16*   h1       = (f16*)(ws + H1_OFF);
    f16*   hx       = (f16*)(ws + HEXP_OFF);
    int*   topk_idx = (int*)(ws + TOPKI_OFF);
    float* topk_w   = (float*)(ws + TOPKW_OFF);
    int*   counts   = (int*)(ws + COUNTS_OFF);
    int*   cursors  = (int*)(ws + CURSORS_OFF);
    int*   offsets  = (int*)(ws + OFFSETS_OFF);
    int*   rtok     = (int*)(ws + RTOK_OFF);
    float* rwt      = (float*)(ws + RW_OFF);

    hipMemsetAsync(counts, 0, 512, stream);   // counts + cursors

    k_router<<<NT / 4, 256, 0, stream>>>(X, Wg, logits);
    k_topk<<<NT, 64, 0, stream>>>(logits, topk_idx, topk_w, counts);
    k_scan<<<1, 64, 0, stream>>>(counts, offsets);
    k_route<<<NT * TOPK / 256, 256, 0, stream>>>(topk_idx, topk_w, offsets, cursors, rtok, rwt);

    k_shared1<<<dim3(FF / 64, NT / 64), 256, 0, stream>>>(X, Ws1, h1);
    k_shared2<<<dim3(HD / 64, NT / 64), 256, 0, stream>>>(h1, Ws2, out);

    k_exp1<<<dim3(MD / 64, NT / 64, NE), 256, 0, stream>>>(X, W1, counts, offsets, rtok, hx);
    k_exp2<<<dim3(HD / 64, NT / 64, NE), 256, 0, stream>>>(hx, W2, counts, offsets, rtok, rwt, out);
}

// Round 2
// 733.930 us; speedup vs baseline: 1.1259x; 1.1259x over previous
//
#include <hip/hip_runtime.h>
#include <cmath>

// DeepSeek MoE layer, MI355X (gfx950). Round 2.
// B=2,S=1024 -> T=2048 tokens. H=1024, FF=4096, E=64, K=8, M=512.
//
// Round-2 changes vs round 1:
//  - Pre-convert all weights fp32 -> fp16 with transpose to [N][K] (k-contiguous)
//    in a BW-bound pre-pass; X -> fp16 once.  (~432 MB => ~80 us)
//  - All 4 GEMMs become m97-style 128x128xBK32 fp16 kernels with
//    __builtin_amdgcn_global_load_lds width=16 staging (no VALU staging, no
//    LDS transpose scatter).  Expert GEMM1 A-rows are gathered per-lane.
//  - shared GEMM2 split-K=4 (zero-init out + atomicAdd) to fill the grid.
//  - Fallback: if ws_size < ~189 MB, run the round-0/1 pipeline (passing).

typedef _Float16 f16;
typedef __attribute__((ext_vector_type(4))) _Float16 f16x4;
typedef __attribute__((ext_vector_type(8))) _Float16 f16x8;
typedef __attribute__((ext_vector_type(4))) float f32x4;

#define NT 2048      // tokens
#define HD 1024      // hidden
#define FF 4096      // shared intermediate
#define NE 64        // experts
#define TOPK 8
#define MD 512       // moe intermediate

// ---- workspace layout (bytes) ----
constexpr size_t SZ_H1 = (size_t)NT * FF * 2;              // fp16 [2048][4096]
constexpr size_t SZ_HX = (size_t)(NT * TOPK + 128) * MD * 2; // fp16 [16512][512]
constexpr size_t O_H1 = 0;
constexpr size_t O_HX = O_H1 + SZ_H1;
constexpr size_t O_TOPKI = O_HX + SZ_HX;
constexpr size_t O_TOPKW = O_TOPKI + (size_t)NT * TOPK * 4;
constexpr size_t O_COUNTS = O_TOPKW + (size_t)NT * TOPK * 4;
constexpr size_t O_CURSORS = O_COUNTS + 256;
constexpr size_t O_OFFSETS = O_CURSORS + 256;
constexpr size_t O_RTOK = O_OFFSETS + 256;
constexpr size_t O_RW = O_RTOK + (size_t)NT * TOPK * 4;
constexpr size_t O_XH = ((O_RW + (size_t)NT * TOPK * 4 + 255) / 256) * 256;
constexpr size_t O_W1T = O_XH + (size_t)NT * HD * 2;       // fp16 [E][M][H]
constexpr size_t O_W2T = O_W1T + (size_t)NE * HD * MD * 2; // fp16 [E][H][M]
constexpr size_t O_WS1T = O_W2T + (size_t)NE * MD * HD * 2;  // fp16 [FF][H]
constexpr size_t O_WS2T = O_WS1T + (size_t)HD * FF * 2;      // fp16 [H][FF]
constexpr size_t WS_NEEDED = O_WS2T + (size_t)FF * HD * 2;   // ~189 MB

// async global->LDS, 16B per lane. LDS dest must be wave-uniform; lane i
// lands at ldsbase + i*16.
__device__ __forceinline__ void lds16(void* l, const void* g) {
    __builtin_amdgcn_global_load_lds(
        (const __attribute__((address_space(1))) void*)g,
        (__attribute__((address_space(3))) void*)l, 16, 0, 0);
}

// ------------------------------------------------------------------
// router: logits[t][e] = dot(x[t], Wg[:,e]) in fp32 (must match numpy top-k).
__global__ __launch_bounds__(256) void k_router(const float* __restrict__ X,
                                                const float* __restrict__ Wg,
                                                float* __restrict__ logits)
{
    __shared__ float xs[4][HD];
    const int tid = threadIdx.x;
    const int t0 = blockIdx.x * 4;
    #pragma unroll
    for (int i = 0; i < 4; ++i) {
        int f4 = tid + i * 256;
        int row = f4 >> 8;
        int col = (f4 & 255) * 4;
        *(float4*)&xs[row][col] = *(const float4*)&X[(t0 + row) * HD + col];
    }
    __syncthreads();
    const int e = tid & 63, tok = tid >> 6;
    float a0 = 0.f, a1 = 0.f, a2 = 0.f, a3 = 0.f;
    const float* xr = xs[tok];
    for (int h = 0; h < HD; h += 4) {
        a0 += xr[h + 0] * Wg[(h + 0) * NE + e];
        a1 += xr[h + 1] * Wg[(h + 1) * NE + e];
        a2 += xr[h + 2] * Wg[(h + 2) * NE + e];
        a3 += xr[h + 3] * Wg[(h + 3) * NE + e];
    }
    logits[(t0 + tok) * NE + e] = (a0 + a1) + (a2 + a3);
}

// top-8 + softmax per token; one wave per token; tie-break lower index.
__global__ __launch_bounds__(64) void k_topk(const float* __restrict__ logits,
                                             int* __restrict__ topk_idx,
                                             float* __restrict__ topk_w,
                                             int* __restrict__ counts)
{
    const int t = blockIdx.x;
    const int lane = threadIdx.x;
    __shared__ float sval[TOPK];
    __shared__ int sidx[TOPK];
    float cur = logits[t * NE + lane];
    for (int it = 0; it < TOPK; ++it) {
        float v = cur; int id = lane;
        #pragma unroll
        for (int off = 32; off > 0; off >>= 1) {
            float ov = __shfl_xor(v, off, 64);
            int   oi = __shfl_xor(id, off, 64);
            if (ov > v || (ov == v && oi < id)) { v = ov; id = oi; }
        }
        if (lane == 0) { sval[it] = v; sidx[it] = id; }
        if (lane == id) cur = -INFINITY;
    }
    __syncthreads();
    if (lane < TOPK) {
        float m = sval[0];
        float denom = 0.f;
        #pragma unroll
        for (int j = 0; j < TOPK; ++j) denom += expf(sval[j] - m);
        float w = expf(sval[lane] - m) / denom;
        int e = sidx[lane];
        topk_idx[t * TOPK + lane] = e;
        topk_w[t * TOPK + lane] = w;
        atomicAdd(&counts[e], 1);
    }
}

__global__ void k_scan(const int* __restrict__ counts, int* __restrict__ offsets)
{
    if (threadIdx.x == 0) {
        int run = 0;
        for (int e = 0; e < NE; ++e) { offsets[e] = run; run += counts[e]; }
    }
}

__global__ __launch_bounds__(256) void k_route(const int* __restrict__ topk_idx,
                                               const float* __restrict__ topk_w,
                                               const int* __restrict__ offsets,
                                               int* __restrict__ cursors,
                                               int* __restrict__ rtok,
                                               float* __restrict__ rw)
{
    int i = blockIdx.x * 256 + threadIdx.x;
    int e = topk_idx[i];
    int pos = atomicAdd(&cursors[e], 1);
    int slot = offsets[e] + pos;
    rtok[slot] = i >> 3;
    rw[slot] = topk_w[i];
}

// ------------------------------------------------------------------
// conversion pre-pass
// X fp32 [T][H] -> fp16 [T][H]
__global__ __launch_bounds__(256) void k_cvt_x(const float* __restrict__ X,
                                               f16* __restrict__ Xh)
{
    int i = blockIdx.x * 256 + threadIdx.x;   // 524288 float4 groups
    float4 v = ((const float4*)X)[i];
    f16x4 h = { (f16)v.x, (f16)v.y, (f16)v.z, (f16)v.w };
    ((f16x4*)Xh)[i] = h;
}

// fp32 [K][N] -> fp16 [N][K] (transpose), batched over blockIdx.z.
__global__ __launch_bounds__(256) void k_cvt_t(const float* __restrict__ src,
                                               f16* __restrict__ dst,
                                               int K, int N)
{
    const size_t bofs = (size_t)blockIdx.z * K * N;
    src += bofs; dst += bofs;
    const int n0 = blockIdx.x * 64, k0 = blockIdx.y * 64;
    __shared__ f16 t[64][68];
    const int tid = threadIdx.x;
    #pragma unroll
    for (int i = 0; i < 4; ++i) {
        int idx = tid + i * 256;
        int r = idx >> 4, c4 = (idx & 15) * 4;
        float4 v = *(const float4*)&src[(size_t)(k0 + r) * N + n0 + c4];
        f16x4 h = { (f16)v.x, (f16)v.y, (f16)v.z, (f16)v.w };
        *(f16x4*)&t[r][c4] = h;
    }
    __syncthreads();
    #pragma unroll
    for (int i = 0; i < 4; ++i) {
        int idx = tid + i * 256;
        int nr = idx >> 4, kc = (idx & 15) * 4;
        f16x4 o = { t[kc][nr], t[kc + 1][nr], t[kc + 2][nr], t[kc + 3][nr] };
        *(f16x4*)&dst[(size_t)(n0 + nr) * K + k0 + kc] = o;
    }
}

// ------------------------------------------------------------------
// m97-style GEMM core: 128x128 tile, BK=32, 256 thr = 4 waves, wave = 64x64
// (4x4 of 16x16x32 MFMA). LDS [128 rows][32 k] f16 contiguous, staged with
// global_load_lds width=16. Fragment mapping verified in round 0/1.

// shared GEMM1: H1 = silu(Xh @ Ws1), fp16. M=2048 N=4096 K=1024.
__global__ __launch_bounds__(256) void g_shared1(const f16* __restrict__ Xh,
                                                 const f16* __restrict__ Bt,  // [FF][HD]
                                                 f16* __restrict__ H1)
{
    __shared__ alignas(16) f16 As[128 * 32];
    __shared__ alignas(16) f16 Bs[128 * 32];
    const int tid = threadIdx.x, lane = tid & 63, wave = tid >> 6;
    const int m0 = blockIdx.y * 128, n0 = blockIdx.x * 128;
    const int wm = (wave >> 1) * 64, wn = (wave & 1) * 64;
    const int fr = lane & 15, q = lane >> 4;
    const int sr = lane >> 2, sc = (lane & 3) * 8;

    const f16* gA0 = Xh + (size_t)(m0 + wave * 32 + sr) * HD + sc;
    const f16* gA1 = gA0 + 16 * HD;
    const f16* gB0 = Bt + (size_t)(n0 + wave * 32 + sr) * HD + sc;
    const f16* gB1 = gB0 + 16 * HD;
    f16* lA0 = &As[(wave * 32) * 32];
    f16* lA1 = &As[(wave * 32 + 16) * 32];
    f16* lB0 = &Bs[(wave * 32) * 32];
    f16* lB1 = &Bs[(wave * 32 + 16) * 32];

    f32x4 acc[4][4] = {};
    for (int kt = 0; kt < HD; kt += 32) {
        lds16(lA0, gA0 + kt); lds16(lA1, gA1 + kt);
        lds16(lB0, gB0 + kt); lds16(lB1, gB1 + kt);
        __syncthreads();
        f16x8 af[4], bf[4];
        #pragma unroll
        for (int i = 0; i < 4; ++i) af[i] = *(const f16x8*)&As[(wm + i * 16 + fr) * 32 + q * 8];
        #pragma unroll
        for (int j = 0; j < 4; ++j) bf[j] = *(const f16x8*)&Bs[(wn + j * 16 + fr) * 32 + q * 8];
        #pragma unroll
        for (int i = 0; i < 4; ++i)
            #pragma unroll
            for (int j = 0; j < 4; ++j)
                acc[i][j] = __builtin_amdgcn_mfma_f32_16x16x32_f16(af[i], bf[j], acc[i][j], 0, 0, 0);
        __syncthreads();
    }
    #pragma unroll
    for (int i = 0; i < 4; ++i)
        #pragma unroll
        for (int j = 0; j < 4; ++j)
            #pragma unroll
            for (int r = 0; r < 4; ++r) {
                int m = m0 + wm + i * 16 + q * 4 + r;
                int n = n0 + wn + j * 16 + fr;
                float v = acc[i][j][r];
                H1[(size_t)m * FF + n] = (f16)(v / (1.f + expf(-v)));
            }
}

// shared GEMM2: Out += H1 @ Ws2, split-K=4 with atomics. M=2048 N=1024 K=4096.
__global__ __launch_bounds__(256) void g_shared2(const f16* __restrict__ H1,
                                                 const f16* __restrict__ Bt,  // [HD][FF]
                                                 float* __restrict__ Out)
{
    __shared__ alignas(16) f16 As[128 * 32];
    __shared__ alignas(16) f16 Bs[128 * 32];
    const int tid = threadIdx.x, lane = tid & 63, wave = tid >> 6;
    const int m0 = blockIdx.y * 128, n0 = blockIdx.x * 128;
    const int kbase = blockIdx.z * (FF / 4);
    const int wm = (wave >> 1) * 64, wn = (wave & 1) * 64;
    const int fr = lane & 15, q = lane >> 4;
    const int sr = lane >> 2, sc = (lane & 3) * 8;

    const f16* gA0 = H1 + (size_t)(m0 + wave * 32 + sr) * FF + kbase + sc;
    const f16* gA1 = gA0 + 16 * FF;
    const f16* gB0 = Bt + (size_t)(n0 + wave * 32 + sr) * FF + kbase + sc;
    const f16* gB1 = gB0 + 16 * FF;
    f16* lA0 = &As[(wave * 32) * 32];
    f16* lA1 = &As[(wave * 32 + 16) * 32];
    f16* lB0 = &Bs[(wave * 32) * 32];
    f16* lB1 = &Bs[(wave * 32 + 16) * 32];

    f32x4 acc[4][4] = {};
    for (int kt = 0; kt < FF / 4; kt += 32) {
        lds16(lA0, gA0 + kt); lds16(lA1, gA1 + kt);
        lds16(lB0, gB0 + kt); lds16(lB1, gB1 + kt);
        __syncthreads();
        f16x8 af[4], bf[4];
        #pragma unroll
        for (int i = 0; i < 4; ++i) af[i] = *(const f16x8*)&As[(wm + i * 16 + fr) * 32 + q * 8];
        #pragma unroll
        for (int j = 0; j < 4; ++j) bf[j] = *(const f16x8*)&Bs[(wn + j * 16 + fr) * 32 + q * 8];
        #pragma unroll
        for (int i = 0; i < 4; ++i)
            #pragma unroll
            for (int j = 0; j < 4; ++j)
                acc[i][j] = __builtin_amdgcn_mfma_f32_16x16x32_f16(af[i], bf[j], acc[i][j], 0, 0, 0);
        __syncthreads();
    }
    #pragma unroll
    for (int i = 0; i < 4; ++i)
        #pragma unroll
        for (int j = 0; j < 4; ++j)
            #pragma unroll
            for (int r = 0; r < 4; ++r) {
                int m = m0 + wm + i * 16 + q * 4 + r;
                int n = n0 + wn + j * 16 + fr;
                atomicAdd(&Out[(size_t)m * HD + n], acc[i][j][r]);
            }
}

// expert GEMM1: Hx[slot] = silu(Xh[rtok[slot]] @ W1[e]) fp16. K=1024 N=512.
__global__ __launch_bounds__(256) void g_exp1(const f16* __restrict__ Xh,
                                              const f16* __restrict__ W1t, // [E][M][H]
                                              const int* __restrict__ counts,
                                              const int* __restrict__ offsets,
                                              const int* __restrict__ rtok,
                                              f16* __restrict__ Hx)
{
    const int e = blockIdx.z;
    const int cnt = counts[e];
    const int mt = blockIdx.y * 128;
    if (mt >= cnt) return;
    const int off = offsets[e];
    const int n0 = blockIdx.x * 128;
    const f16* W = W1t + (size_t)e * MD * HD;

    __shared__ alignas(16) f16 As[128 * 32];
    __shared__ alignas(16) f16 Bs[128 * 32];
    const int tid = threadIdx.x, lane = tid & 63, wave = tid >> 6;
    const int wm = (wave >> 1) * 64, wn = (wave & 1) * 64;
    const int fr = lane & 15, q = lane >> 4;
    const int sr = lane >> 2, sc = (lane & 3) * 8;

    // gathered A rows (per-lane global addresses; clamp OOB to a valid slot)
    int rm0 = mt + wave * 32 + sr;
    int rm1 = rm0 + 16;
    int s0 = off + (rm0 < cnt ? rm0 : cnt - 1);
    int s1 = off + (rm1 < cnt ? rm1 : cnt - 1);
    const f16* gA0 = Xh + (size_t)rtok[s0] * HD + sc;
    const f16* gA1 = Xh + (size_t)rtok[s1] * HD + sc;
    const f16* gB0 = W + (size_t)(n0 + wave * 32 + sr) * HD + sc;
    const f16* gB1 = gB0 + 16 * HD;
    f16* lA0 = &As[(wave * 32) * 32];
    f16* lA1 = &As[(wave * 32 + 16) * 32];
    f16* lB0 = &Bs[(wave * 32) * 32];
    f16* lB1 = &Bs[(wave * 32 + 16) * 32];

    f32x4 acc[4][4] = {};
    for (int kt = 0; kt < HD; kt += 32) {
        lds16(lA0, gA0 + kt); lds16(lA1, gA1 + kt);
        lds16(lB0, gB0 + kt); lds16(lB1, gB1 + kt);
        __syncthreads();
        f16x8 af[4], bf[4];
        #pragma unroll
        for (int i = 0; i < 4; ++i) af[i] = *(const f16x8*)&As[(wm + i * 16 + fr) * 32 + q * 8];
        #pragma unroll
        for (int j = 0; j < 4; ++j) bf[j] = *(const f16x8*)&Bs[(wn + j * 16 + fr) * 32 + q * 8];
        #pragma unroll
        for (int i = 0; i < 4; ++i)
            #pragma unroll
            for (int j = 0; j < 4; ++j)
                acc[i][j] = __builtin_amdgcn_mfma_f32_16x16x32_f16(af[i], bf[j], acc[i][j], 0, 0, 0);
        __syncthreads();
    }
    #pragma unroll
    for (int i = 0; i < 4; ++i)
        #pragma unroll
        for (int j = 0; j < 4; ++j)
            #pragma unroll
            for (int r = 0; r < 4; ++r) {
                int m_in = mt + wm + i * 16 + q * 4 + r;
                if (m_in < cnt) {
                    int n = n0 + wn + j * 16 + fr;
                    float v = acc[i][j][r];
                    Hx[(size_t)(off + m_in) * MD + n] = (f16)(v / (1.f + expf(-v)));
                }
            }
}

// expert GEMM2: Out[t] += w * (Hx @ W2[e]). K=512 N=1024, atomic scatter.
__global__ __launch_bounds__(256) void g_exp2(const f16* __restrict__ Hx,
                                              const f16* __restrict__ W2t, // [E][H][M]
                                              const int* __restrict__ counts,
                                              const int* __restrict__ offsets,
                                              const int* __restrict__ rtok,
                                              const float* __restrict__ rw,
                                              float* __restrict__ Out)
{
    const int e = blockIdx.z;
    const int cnt = counts[e];
    const int mt = blockIdx.y * 128;
    if (mt >= cnt) return;
    const int off = offsets[e];
    const int n0 = blockIdx.x * 128;
    const f16* W = W2t + (size_t)e * HD * MD;

    __shared__ alignas(16) f16 As[128 * 32];
    __shared__ alignas(16) f16 Bs[128 * 32];
    const int tid = threadIdx.x, lane = tid & 63, wave = tid >> 6;
    const int wm = (wave >> 1) * 64, wn = (wave & 1) * 64;
    const int fr = lane & 15, q = lane >> 4;
    const int sr = lane >> 2, sc = (lane & 3) * 8;

    // A rows are packed slots; Hx has 128 pad rows so OOB rows read garbage
    // (finite) and are masked at the C-write.
    const f16* gA0 = Hx + (size_t)(off + mt + wave * 32 + sr) * MD + sc;
    const f16* gA1 = gA0 + 16 * MD;
    const f16* gB0 = W + (size_t)(n0 + wave * 32 + sr) * MD + sc;
    const f16* gB1 = gB0 + 16 * MD;
    f16* lA0 = &As[(wave * 32) * 32];
    f16* lA1 = &As[(wave * 32 + 16) * 32];
    f16* lB0 = &Bs[(wave * 32) * 32];
    f16* lB1 = &Bs[(wave * 32 + 16) * 32];

    f32x4 acc[4][4] = {};
    for (int kt = 0; kt < MD; kt += 32) {
        lds16(lA0, gA0 + kt); lds16(lA1, gA1 + kt);
        lds16(lB0, gB0 + kt); lds16(lB1, gB1 + kt);
        __syncthreads();
        f16x8 af[4], bf[4];
        #pragma unroll
        for (int i = 0; i < 4; ++i) af[i] = *(const f16x8*)&As[(wm + i * 16 + fr) * 32 + q * 8];
        #pragma unroll
        for (int j = 0; j < 4; ++j) bf[j] = *(const f16x8*)&Bs[(wn + j * 16 + fr) * 32 + q * 8];
        #pragma unroll
        for (int i = 0; i < 4; ++i)
            #pragma unroll
            for (int j = 0; j < 4; ++j)
                acc[i][j] = __builtin_amdgcn_mfma_f32_16x16x32_f16(af[i], bf[j], acc[i][j], 0, 0, 0);
        __syncthreads();
    }
    #pragma unroll
    for (int i = 0; i < 4; ++i)
        #pragma unroll
        for (int r = 0; r < 4; ++r) {
            int m_in = mt + wm + i * 16 + q * 4 + r;
            if (m_in < cnt) {
                int slot = off + m_in;
                int t = rtok[slot];
                float w = rw[slot];
                float* orow = Out + (size_t)t * HD + n0 + wn + fr;
                #pragma unroll
                for (int j = 0; j < 4; ++j)
                    atomicAdd(&orow[j * 16], w * acc[i][j][r]);
            }
        }
}

// ==================================================================
// Fallback pipeline (round-0/1, passing): 64x64 tiles, fp32 weights,
// in-kernel cvt. Used only if ws_size < WS_NEEDED.
__global__ __launch_bounds__(256) void k_shared1(const float* __restrict__ X,
                                                 const float* __restrict__ W,
                                                 f16* __restrict__ H1)
{
    __shared__ alignas(16) f16 As[64][40];
    __shared__ alignas(16) f16 Bs[64][40];
    const int tid = threadIdx.x;
    const int n0 = blockIdx.x * 64, m0 = blockIdx.y * 64;
    const int lane = tid & 63, wave = tid >> 6;
    const int wm = (wave >> 1) * 32, wn = (wave & 1) * 32;
    const int fr = lane & 15, q = lane >> 4;
    f32x4 acc[2][2] = {};
    for (int kt = 0; kt < HD; kt += 32) {
        #pragma unroll
        for (int i = 0; i < 2; ++i) {
            int f = tid + i * 256;
            int r = f >> 3, c = (f & 7) * 4;
            float4 v = *(const float4*)&X[(m0 + r) * HD + kt + c];
            f16x4 h = { (f16)v.x, (f16)v.y, (f16)v.z, (f16)v.w };
            *(f16x4*)&As[r][c] = h;
        }
        #pragma unroll
        for (int i = 0; i < 8; ++i) {
            int g = tid + i * 256;
            int k = g >> 6, n = g & 63;
            Bs[n][k] = (f16)W[(kt + k) * FF + n0 + n];
        }
        __syncthreads();
        f16x8 a0 = *(const f16x8*)&As[wm + fr][q * 8];
        f16x8 a1 = *(const f16x8*)&As[wm + 16 + fr][q * 8];
        f16x8 b0 = *(const f16x8*)&Bs[wn + fr][q * 8];
        f16x8 b1 = *(const f16x8*)&Bs[wn + 16 + fr][q * 8];
        acc[0][0] = __builtin_amdgcn_mfma_f32_16x16x32_f16(a0, b0, acc[0][0], 0, 0, 0);
        acc[0][1] = __builtin_amdgcn_mfma_f32_16x16x32_f16(a0, b1, acc[0][1], 0, 0, 0);
        acc[1][0] = __builtin_amdgcn_mfma_f32_16x16x32_f16(a1, b0, acc[1][0], 0, 0, 0);
        acc[1][1] = __builtin_amdgcn_mfma_f32_16x16x32_f16(a1, b1, acc[1][1], 0, 0, 0);
        __syncthreads();
    }
    #pragma unroll
    for (int i = 0; i < 2; ++i)
        #pragma unroll
        for (int j = 0; j < 2; ++j)
            #pragma unroll
            for (int r = 0; r < 4; ++r) {
                int m = m0 + wm + i * 16 + q * 4 + r;
                int n = n0 + wn + j * 16 + fr;
                float v = acc[i][j][r];
                H1[m * FF + n] = (f16)(v / (1.f + expf(-v)));
            }
}

__global__ __launch_bounds__(256) void k_shared2(const f16* __restrict__ H1,
                                                 const float* __restrict__ W,
                                                 float* __restrict__ Out)
{
    __shared__ alignas(16) f16 As[64][40];
    __shared__ alignas(16) f16 Bs[64][40];
    const int tid = threadIdx.x;
    const int n0 = blockIdx.x * 64, m0 = blockIdx.y * 64;
    const int lane = tid & 63, wave = tid >> 6;
    const int wm = (wave >> 1) * 32, wn = (wave & 1) * 32;
    const int fr = lane & 15, q = lane >> 4;
    f32x4 acc[2][2] = {};
    for (int kt = 0; kt < FF; kt += 32) {
        {
            int r = tid >> 2, c = (tid & 3) * 8;
            f16x8 v = *(const f16x8*)&H1[(m0 + r) * FF + kt + c];
            *(f16x8*)&As[r][c] = v;
        }
        #pragma unroll
        for (int i = 0; i < 8; ++i) {
            int g = tid + i * 256;
            int k = g >> 6, n = g & 63;
            Bs[n][k] = (f16)W[(kt + k) * HD + n0 + n];
        }
        __syncthreads();
        f16x8 a0 = *(const f16x8*)&As[wm + fr][q * 8];
        f16x8 a1 = *(const f16x8*)&As[wm + 16 + fr][q * 8];
        f16x8 b0 = *(const f16x8*)&Bs[wn + fr][q * 8];
        f16x8 b1 = *(const f16x8*)&Bs[wn + 16 + fr][q * 8];
        acc[0][0] = __builtin_amdgcn_mfma_f32_16x16x32_f16(a0, b0, acc[0][0], 0, 0, 0);
        acc[0][1] = __builtin_amdgcn_mfma_f32_16x16x32_f16(a0, b1, acc[0][1], 0, 0, 0);
        acc[1][0] = __builtin_amdgcn_mfma_f32_16x16x32_f16(a1, b0, acc[1][0], 0, 0, 0);
        acc[1][1] = __builtin_amdgcn_mfma_f32_16x16x32_f16(a1, b1, acc[1][1], 0, 0, 0);
        __syncthreads();
    }
    #pragma unroll
    for (int i = 0; i < 2; ++i)
        #pragma unroll
        for (int j = 0; j < 2; ++j)
            #pragma unroll
            for (int r = 0; r < 4; ++r) {
                int m = m0 + wm + i * 16 + q * 4 + r;
                int n = n0 + wn + j * 16 + fr;
                Out[m * HD + n] = acc[i][j][r];
            }
}

__global__ __launch_bounds__(256) void k_exp1(const float* __restrict__ X,
                                              const float* __restrict__ W1,
                                              const int* __restrict__ counts,
                                              const int* __restrict__ offsets,
                                              const int* __restrict__ rtok,
                                              f16* __restrict__ Hx)
{
    const int e = blockIdx.z;
    const int cnt = counts[e];
    const int mt = blockIdx.y * 64;
    if (mt >= cnt) return;
    const int off = offsets[e];
    const int n0 = blockIdx.x * 64;
    const float* W = W1 + (size_t)e * HD * MD;
    __shared__ alignas(16) f16 As[64][40];
    __shared__ alignas(16) f16 Bs[64][40];
    const int tid = threadIdx.x;
    const int lane = tid & 63, wave = tid >> 6;
    const int wm = (wave >> 1) * 32, wn = (wave & 1) * 32;
    const int fr = lane & 15, q = lane >> 4;
    const int r_a = tid >> 3;
    const int c = (tid & 7) * 4;
    const int mr_a = mt + r_a, mr_b = mt + r_a + 32;
    const bool va = mr_a < cnt, vb = mr_b < cnt;
    const float* xa = X + (va ? (size_t)rtok[off + mr_a] * HD : 0);
    const float* xb = X + (vb ? (size_t)rtok[off + mr_b] * HD : 0);
    f32x4 acc[2][2] = {};
    for (int kt = 0; kt < HD; kt += 32) {
        {
            float4 v = {0.f, 0.f, 0.f, 0.f};
            if (va) v = *(const float4*)&xa[kt + c];
            f16x4 h = { (f16)v.x, (f16)v.y, (f16)v.z, (f16)v.w };
            *(f16x4*)&As[r_a][c] = h;
            float4 u = {0.f, 0.f, 0.f, 0.f};
            if (vb) u = *(const float4*)&xb[kt + c];
            f16x4 h2 = { (f16)u.x, (f16)u.y, (f16)u.z, (f16)u.w };
            *(f16x4*)&As[r_a + 32][c] = h2;
        }
        #pragma unroll
        for (int i = 0; i < 8; ++i) {
            int g = tid + i * 256;
            int k = g >> 6, n = g & 63;
            Bs[n][k] = (f16)W[(kt + k) * MD + n0 + n];
        }
        __syncthreads();
        f16x8 a0 = *(const f16x8*)&As[wm + fr][q * 8];
        f16x8 a1 = *(const f16x8*)&As[wm + 16 + fr][q * 8];
        f16x8 b0 = *(const f16x8*)&Bs[wn + fr][q * 8];
        f16x8 b1 = *(const f16x8*)&Bs[wn + 16 + fr][q * 8];
        acc[0][0] = __builtin_amdgcn_mfma_f32_16x16x32_f16(a0, b0, acc[0][0], 0, 0, 0);
        acc[0][1] = __builtin_amdgcn_mfma_f32_16x16x32_f16(a0, b1, acc[0][1], 0, 0, 0);
        acc[1][0] = __builtin_amdgcn_mfma_f32_16x16x32_f16(a1, b0, acc[1][0], 0, 0, 0);
        acc[1][1] = __builtin_amdgcn_mfma_f32_16x16x32_f16(a1, b1, acc[1][1], 0, 0, 0);
        __syncthreads();
    }
    #pragma unroll
    for (int i = 0; i < 2; ++i)
        #pragma unroll
        for (int j = 0; j < 2; ++j)
            #pragma unroll
            for (int r = 0; r < 4; ++r) {
                int m_in = mt + wm + i * 16 + q * 4 + r;
                if (m_in < cnt) {
                    int n = n0 + wn + j * 16 + fr;
                    float v = acc[i][j][r];
                    Hx[(size_t)(off + m_in) * MD + n] = (f16)(v / (1.f + expf(-v)));
                }
            }
}

__global__ __launch_bounds__(256) void k_exp2(const f16* __restrict__ Hx,
                                              const float* __restrict__ W2,
                                              const int* __restrict__ counts,
                                              const int* __restrict__ offsets,
                                              const int* __restrict__ rtok,
                                              const float* __restrict__ rw,
                                              float* __restrict__ Out)
{
    const int e = blockIdx.z;
    const int cnt = counts[e];
    const int mt = blockIdx.y * 64;
    if (mt >= cnt) return;
    const int off = offsets[e];
    const int n0 = blockIdx.x * 64;
    const float* W = W2 + (size_t)e * MD * HD;
    __shared__ alignas(16) f16 As[64][40];
    __shared__ alignas(16) f16 Bs[64][40];
    const int tid = threadIdx.x;
    const int lane = tid & 63, wave = tid >> 6;
    const int wm = (wave >> 1) * 32, wn = (wave & 1) * 32;
    const int fr = lane & 15, q = lane >> 4;
    f32x4 acc[2][2] = {};
    for (int kt = 0; kt < MD; kt += 32) {
        {
            int r = tid >> 2, c = (tid & 3) * 8;
            f16x8 v = *(const f16x8*)&Hx[(size_t)(off + mt + r) * MD + kt + c];
            *(f16x8*)&As[r][c] = v;
        }
        #pragma unroll
        for (int i = 0; i < 8; ++i) {
            int g = tid + i * 256;
            int k = g >> 6, n = g & 63;
            Bs[n][k] = (f16)W[(kt + k) * HD + n0 + n];
        }
        __syncthreads();
        f16x8 a0 = *(const f16x8*)&As[wm + fr][q * 8];
        f16x8 a1 = *(const f16x8*)&As[wm + 16 + fr][q * 8];
        f16x8 b0 = *(const f16x8*)&Bs[wn + fr][q * 8];
        f16x8 b1 = *(const f16x8*)&Bs[wn + 16 + fr][q * 8];
        acc[0][0] = __builtin_amdgcn_mfma_f32_16x16x32_f16(a0, b0, acc[0][0], 0, 0, 0);
        acc[0][1] = __builtin_amdgcn_mfma_f32_16x16x32_f16(a0, b1, acc[0][1], 0, 0, 0);
        acc[1][0] = __builtin_amdgcn_mfma_f32_16x16x32_f16(a1, b0, acc[1][0], 0, 0, 0);
        acc[1][1] = __builtin_amdgcn_mfma_f32_16x16x32_f16(a1, b1, acc[1][1], 0, 0, 0);
        __syncthreads();
    }
    #pragma unroll
    for (int i = 0; i < 2; ++i)
        #pragma unroll
        for (int j = 0; j < 2; ++j)
            #pragma unroll
            for (int r = 0; r < 4; ++r) {
                int m_in = mt + wm + i * 16 + q * 4 + r;
                if (m_in < cnt) {
                    int slot = off + m_in;
                    int t = rtok[slot];
                    float w = rw[slot];
                    int n = n0 + wn + j * 16 + fr;
                    atomicAdd(&Out[(size_t)t * HD + n], w * acc[i][j][r]);
                }
            }
}

// ------------------------------------------------------------------
extern "C" void kernel_launch(void* const* d_in, const int* in_sizes, int n_in,
                              void* d_out, int out_size, void* d_ws, size_t ws_size,
                              hipStream_t stream)
{
    (void)in_sizes; (void)n_in; (void)out_size;
    const float* X   = (const float*)d_in[0];
    const float* Ws1 = (const float*)d_in[1];
    const float* Ws2 = (const float*)d_in[2];
    const float* Wg  = (const float*)d_in[3];
    const float* W1  = (const float*)d_in[4];
    const float* W2  = (const float*)d_in[5];
    float* out = (float*)d_out;
    float* logits = out + (size_t)NT * HD;

    char* ws = (char*)d_ws;
    f16*   h1       = (f16*)(ws + O_H1);
    f16*   hx       = (f16*)(ws + O_HX);
    int*   topk_idx = (int*)(ws + O_TOPKI);
    float* topk_w   = (float*)(ws + O_TOPKW);
    int*   counts   = (int*)(ws + O_COUNTS);
    int*   cursors  = (int*)(ws + O_CURSORS);
    int*   offsets  = (int*)(ws + O_OFFSETS);
    int*   rtok     = (int*)(ws + O_RTOK);
    float* rwt      = (float*)(ws + O_RW);
    f16*   xh       = (f16*)(ws + O_XH);
    f16*   w1t      = (f16*)(ws + O_W1T);
    f16*   w2t      = (f16*)(ws + O_W2T);
    f16*   ws1t     = (f16*)(ws + O_WS1T);
    f16*   ws2t     = (f16*)(ws + O_WS2T);

    hipMemsetAsync(counts, 0, 512, stream);   // counts + cursors

    k_router<<<NT / 4, 256, 0, stream>>>(X, Wg, logits);
    k_topk<<<NT, 64, 0, stream>>>(logits, topk_idx, topk_w, counts);
    k_scan<<<1, 64, 0, stream>>>(counts, offsets);
    k_route<<<NT * TOPK / 256, 256, 0, stream>>>(topk_idx, topk_w, offsets, cursors, rtok, rwt);

    if (ws_size >= WS_NEEDED) {
        // conversion pre-pass
        k_cvt_x<<<NT * HD / 1024, 256, 0, stream>>>(X, xh);
        k_cvt_t<<<dim3(FF / 64, HD / 64, 1), 256, 0, stream>>>(Ws1, ws1t, HD, FF);
        k_cvt_t<<<dim3(HD / 64, FF / 64, 1), 256, 0, stream>>>(Ws2, ws2t, FF, HD);
        k_cvt_t<<<dim3(MD / 64, HD / 64, NE), 256, 0, stream>>>(W1, w1t, HD, MD);
        k_cvt_t<<<dim3(HD / 64, MD / 64, NE), 256, 0, stream>>>(W2, w2t, MD, HD);
        hipMemsetAsync(out, 0, (size_t)NT * HD * 4, stream);

        g_shared1<<<dim3(FF / 128, NT / 128), 256, 0, stream>>>(xh, ws1t, h1);
        g_shared2<<<dim3(HD / 128, NT / 128, 4), 256, 0, stream>>>(h1, ws2t, out);
        g_exp1<<<dim3(MD / 128, NT / 128, NE), 256, 0, stream>>>(xh, w1t, counts, offsets, rtok, hx);
        g_exp2<<<dim3(HD / 128, NT / 128, NE), 256, 0, stream>>>(hx, w2t, counts, offsets, rtok, rwt, out);
    } else {
        // fallback (round-0/1 pipeline)
        k_shared1<<<dim3(FF / 64, NT / 64), 256, 0, stream>>>(X, Ws1, h1);
        k_shared2<<<dim3(HD / 64, NT / 64), 256, 0, stream>>>(h1, Ws2, out);
        k_exp1<<<dim3(MD / 64, NT / 64, NE), 256, 0, stream>>>(X, W1, counts, offsets, rtok, hx);
        k_exp2<<<dim3(HD / 64, NT / 64, NE), 256, 0, stream>>>(hx, W2, counts, offsets, rtok, rwt, out);
    }
}

// Round 3
// 712.359 us; speedup vs baseline: 1.1599x; 1.0303x over previous
//
#include <hip/hip_runtime.h>
#include <cmath>

// DeepSeek MoE layer, MI355X (gfx950). Round 3.
// B=2,S=1024 -> T=2048 tokens. H=1024, FF=4096, E=64, K=8, M=512.
//
// Round-3 changes vs round 2 (which was latency/occupancy-bound:
// MfmaUtil 7%, Occupancy 9% on g_exp1):
//  - BM 128 -> 64 on all GEMMs: active block counts 512..2048 (4-8/CU).
//  - Double-buffered LDS K-loop, ONE barrier per iter; next tile's
//    global_load_lds issued after the barrier so the compiler's
//    vmcnt(0)-before-barrier drains loads that already had a full MFMA
//    block in flight.
//  - Tile = 64x128xBK32, 4 waves (2x2), wave = 32x64 = acc[2][4],
//    8 MFMA + 3 lds16 stages per iter per wave.

typedef _Float16 f16;
typedef __attribute__((ext_vector_type(4))) _Float16 f16x4;
typedef __attribute__((ext_vector_type(8))) _Float16 f16x8;
typedef __attribute__((ext_vector_type(4))) float f32x4;

#define NT 2048      // tokens
#define HD 1024      // hidden
#define FF 4096      // shared intermediate
#define NE 64        // experts
#define TOPK 8
#define MD 512       // moe intermediate

// ---- workspace layout (bytes) ----
constexpr size_t SZ_H1 = (size_t)NT * FF * 2;                // fp16 [2048][4096]
constexpr size_t SZ_HX = (size_t)(NT * TOPK + 128) * MD * 2; // fp16 [16512][512]
constexpr size_t O_H1 = 0;
constexpr size_t O_HX = O_H1 + SZ_H1;
constexpr size_t O_TOPKI = O_HX + SZ_HX;
constexpr size_t O_TOPKW = O_TOPKI + (size_t)NT * TOPK * 4;
constexpr size_t O_COUNTS = O_TOPKW + (size_t)NT * TOPK * 4;
constexpr size_t O_CURSORS = O_COUNTS + 256;
constexpr size_t O_OFFSETS = O_CURSORS + 256;
constexpr size_t O_RTOK = O_OFFSETS + 256;
constexpr size_t O_RW = O_RTOK + (size_t)NT * TOPK * 4;
constexpr size_t O_XH = ((O_RW + (size_t)NT * TOPK * 4 + 255) / 256) * 256;
constexpr size_t O_W1T = O_XH + (size_t)NT * HD * 2;         // fp16 [E][M][H]
constexpr size_t O_W2T = O_W1T + (size_t)NE * HD * MD * 2;   // fp16 [E][H][M]
constexpr size_t O_WS1T = O_W2T + (size_t)NE * MD * HD * 2;  // fp16 [FF][H]
constexpr size_t O_WS2T = O_WS1T + (size_t)HD * FF * 2;      // fp16 [H][FF]
constexpr size_t WS_NEEDED = O_WS2T + (size_t)FF * HD * 2;   // ~189 MB

// async global->LDS, 16B per lane; lane i lands at ldsbase + i*16.
__device__ __forceinline__ void lds16(void* l, const void* g) {
    __builtin_amdgcn_global_load_lds(
        (const __attribute__((address_space(1))) void*)g,
        (__attribute__((address_space(3))) void*)l, 16, 0, 0);
}

// ------------------------------------------------------------------
// router: logits[t][e] = dot(x[t], Wg[:,e]) in fp32 (must match numpy top-k).
__global__ __launch_bounds__(256) void k_router(const float* __restrict__ X,
                                                const float* __restrict__ Wg,
                                                float* __restrict__ logits)
{
    __shared__ float xs[4][HD];
    const int tid = threadIdx.x;
    const int t0 = blockIdx.x * 4;
    #pragma unroll
    for (int i = 0; i < 4; ++i) {
        int f4 = tid + i * 256;
        int row = f4 >> 8;
        int col = (f4 & 255) * 4;
        *(float4*)&xs[row][col] = *(const float4*)&X[(t0 + row) * HD + col];
    }
    __syncthreads();
    const int e = tid & 63, tok = tid >> 6;
    float a0 = 0.f, a1 = 0.f, a2 = 0.f, a3 = 0.f;
    const float* xr = xs[tok];
    for (int h = 0; h < HD; h += 4) {
        a0 += xr[h + 0] * Wg[(h + 0) * NE + e];
        a1 += xr[h + 1] * Wg[(h + 1) * NE + e];
        a2 += xr[h + 2] * Wg[(h + 2) * NE + e];
        a3 += xr[h + 3] * Wg[(h + 3) * NE + e];
    }
    logits[(t0 + tok) * NE + e] = (a0 + a1) + (a2 + a3);
}

// top-8 + softmax per token; one wave per token; tie-break lower index.
__global__ __launch_bounds__(64) void k_topk(const float* __restrict__ logits,
                                             int* __restrict__ topk_idx,
                                             float* __restrict__ topk_w,
                                             int* __restrict__ counts)
{
    const int t = blockIdx.x;
    const int lane = threadIdx.x;
    __shared__ float sval[TOPK];
    __shared__ int sidx[TOPK];
    float cur = logits[t * NE + lane];
    for (int it = 0; it < TOPK; ++it) {
        float v = cur; int id = lane;
        #pragma unroll
        for (int off = 32; off > 0; off >>= 1) {
            float ov = __shfl_xor(v, off, 64);
            int   oi = __shfl_xor(id, off, 64);
            if (ov > v || (ov == v && oi < id)) { v = ov; id = oi; }
        }
        if (lane == 0) { sval[it] = v; sidx[it] = id; }
        if (lane == id) cur = -INFINITY;
    }
    __syncthreads();
    if (lane < TOPK) {
        float m = sval[0];
        float denom = 0.f;
        #pragma unroll
        for (int j = 0; j < TOPK; ++j) denom += expf(sval[j] - m);
        float w = expf(sval[lane] - m) / denom;
        int e = sidx[lane];
        topk_idx[t * TOPK + lane] = e;
        topk_w[t * TOPK + lane] = w;
        atomicAdd(&counts[e], 1);
    }
}

__global__ void k_scan(const int* __restrict__ counts, int* __restrict__ offsets)
{
    if (threadIdx.x == 0) {
        int run = 0;
        for (int e = 0; e < NE; ++e) { offsets[e] = run; run += counts[e]; }
    }
}

__global__ __launch_bounds__(256) void k_route(const int* __restrict__ topk_idx,
                                               const float* __restrict__ topk_w,
                                               const int* __restrict__ offsets,
                                               int* __restrict__ cursors,
                                               int* __restrict__ rtok,
                                               float* __restrict__ rw)
{
    int i = blockIdx.x * 256 + threadIdx.x;
    int e = topk_idx[i];
    int pos = atomicAdd(&cursors[e], 1);
    int slot = offsets[e] + pos;
    rtok[slot] = i >> 3;
    rw[slot] = topk_w[i];
}

// ------------------------------------------------------------------
// conversion pre-pass
__global__ __launch_bounds__(256) void k_cvt_x(const float* __restrict__ X,
                                               f16* __restrict__ Xh)
{
    int i = blockIdx.x * 256 + threadIdx.x;
    float4 v = ((const float4*)X)[i];
    f16x4 h = { (f16)v.x, (f16)v.y, (f16)v.z, (f16)v.w };
    ((f16x4*)Xh)[i] = h;
}

// fp32 [K][N] -> fp16 [N][K] (transpose), batched over blockIdx.z.
__global__ __launch_bounds__(256) void k_cvt_t(const float* __restrict__ src,
                                               f16* __restrict__ dst,
                                               int K, int N)
{
    const size_t bofs = (size_t)blockIdx.z * K * N;
    src += bofs; dst += bofs;
    const int n0 = blockIdx.x * 64, k0 = blockIdx.y * 64;
    __shared__ f16 t[64][68];
    const int tid = threadIdx.x;
    #pragma unroll
    for (int i = 0; i < 4; ++i) {
        int idx = tid + i * 256;
        int r = idx >> 4, c4 = (idx & 15) * 4;
        float4 v = *(const float4*)&src[(size_t)(k0 + r) * N + n0 + c4];
        f16x4 h = { (f16)v.x, (f16)v.y, (f16)v.z, (f16)v.w };
        *(f16x4*)&t[r][c4] = h;
    }
    __syncthreads();
    #pragma unroll
    for (int i = 0; i < 4; ++i) {
        int idx = tid + i * 256;
        int nr = idx >> 4, kc = (idx & 15) * 4;
        f16x4 o = { t[kc][nr], t[kc + 1][nr], t[kc + 2][nr], t[kc + 3][nr] };
        *(f16x4*)&dst[(size_t)(n0 + nr) * K + k0 + kc] = o;
    }
}

// ------------------------------------------------------------------
// GEMM core: 64x128 tile, BK=32, 4 waves (2 M-halves x 2 N-halves),
// wave = 32x64 = acc[2][4]. Double-buffered LDS, one barrier/iter.
// LDS per buffer: As 64x32, Bs 128x32 (f16, k-contiguous rows).
// Frag mapping (verified r0-r2): A[m=fr][k=q*8+j], B[n=fr][k=q*8+j],
// C/D col=fr, row=q*4+reg.

#define GEMM_PREAMBLE                                                        \
    const int tid = threadIdx.x, lane = tid & 63, wave = tid >> 6;           \
    const int wm = (wave >> 1) * 32, wn = (wave & 1) * 64;                   \
    const int fr = lane & 15, q = lane >> 4;                                 \
    const int sr = lane >> 2, sc = (lane & 3) * 8;

#define GEMM_STAGE(buf, ofs)                                                 \
    lds16(&As[buf][wave * 16 * 32], gA + (ofs));                             \
    lds16(&Bs[buf][wave * 32 * 32], gB0 + (ofs));                            \
    lds16(&Bs[buf][(wave * 32 + 16) * 32], gB1 + (ofs));

#define GEMM_MFMA(buf)                                                       \
    {                                                                        \
        f16x8 af[2], bf[4];                                                  \
        _Pragma("unroll")                                                    \
        for (int i = 0; i < 2; ++i)                                          \
            af[i] = *(const f16x8*)&As[buf][(wm + i * 16 + fr) * 32 + q * 8];\
        _Pragma("unroll")                                                    \
        for (int j = 0; j < 4; ++j)                                          \
            bf[j] = *(const f16x8*)&Bs[buf][(wn + j * 16 + fr) * 32 + q * 8];\
        _Pragma("unroll")                                                    \
        for (int i = 0; i < 2; ++i)                                          \
            _Pragma("unroll")                                                \
            for (int j = 0; j < 4; ++j)                                      \
                acc[i][j] = __builtin_amdgcn_mfma_f32_16x16x32_f16(          \
                    af[i], bf[j], acc[i][j], 0, 0, 0);                       \
    }

// shared GEMM1: H1 = silu(Xh @ Ws1), fp16. M=2048 N=4096 K=1024.
__global__ __launch_bounds__(256) void g_shared1(const f16* __restrict__ Xh,
                                                 const f16* __restrict__ Bt,  // [FF][HD]
                                                 f16* __restrict__ H1)
{
    __shared__ alignas(16) f16 As[2][64 * 32];
    __shared__ alignas(16) f16 Bs[2][128 * 32];
    GEMM_PREAMBLE
    const int m0 = blockIdx.y * 64, n0 = blockIdx.x * 128;
    const f16* gA = Xh + (size_t)(m0 + wave * 16 + sr) * HD + sc;
    const f16* gB0 = Bt + (size_t)(n0 + wave * 32 + sr) * HD + sc;
    const f16* gB1 = gB0 + 16 * HD;

    f32x4 acc[2][4] = {};
    GEMM_STAGE(0, 0)
    int par = 0;
    for (int kt = 0; kt < HD; kt += 32) {
        __syncthreads();
        if (kt + 32 < HD) { int np = par ^ 1; GEMM_STAGE(np, kt + 32) }
        GEMM_MFMA(par)
        par ^= 1;
    }
    #pragma unroll
    for (int i = 0; i < 2; ++i)
        #pragma unroll
        for (int j = 0; j < 4; ++j)
            #pragma unroll
            for (int r = 0; r < 4; ++r) {
                int m = m0 + wm + i * 16 + q * 4 + r;
                int n = n0 + wn + j * 16 + fr;
                float v = acc[i][j][r];
                H1[(size_t)m * FF + n] = (f16)(v / (1.f + expf(-v)));
            }
}

// shared GEMM2: Out += H1 @ Ws2, split-K=4 atomics. M=2048 N=1024 K=4096.
__global__ __launch_bounds__(256) void g_shared2(const f16* __restrict__ H1,
                                                 const f16* __restrict__ Bt,  // [HD][FF]
                                                 float* __restrict__ Out)
{
    __shared__ alignas(16) f16 As[2][64 * 32];
    __shared__ alignas(16) f16 Bs[2][128 * 32];
    GEMM_PREAMBLE
    const int m0 = blockIdx.y * 64, n0 = blockIdx.x * 128;
    const int kbase = blockIdx.z * (FF / 4);
    const f16* gA = H1 + (size_t)(m0 + wave * 16 + sr) * FF + kbase + sc;
    const f16* gB0 = Bt + (size_t)(n0 + wave * 32 + sr) * FF + kbase + sc;
    const f16* gB1 = gB0 + 16 * FF;

    f32x4 acc[2][4] = {};
    GEMM_STAGE(0, 0)
    int par = 0;
    for (int kt = 0; kt < FF / 4; kt += 32) {
        __syncthreads();
        if (kt + 32 < FF / 4) { int np = par ^ 1; GEMM_STAGE(np, kt + 32) }
        GEMM_MFMA(par)
        par ^= 1;
    }
    #pragma unroll
    for (int i = 0; i < 2; ++i)
        #pragma unroll
        for (int j = 0; j < 4; ++j)
            #pragma unroll
            for (int r = 0; r < 4; ++r) {
                int m = m0 + wm + i * 16 + q * 4 + r;
                int n = n0 + wn + j * 16 + fr;
                atomicAdd(&Out[(size_t)m * HD + n], acc[i][j][r]);
            }
}

// expert GEMM1: Hx[slot] = silu(Xh[rtok[slot]] @ W1[e]) fp16. K=1024 N=512.
__global__ __launch_bounds__(256) void g_exp1(const f16* __restrict__ Xh,
                                              const f16* __restrict__ W1t, // [E][M][H]
                                              const int* __restrict__ counts,
                                              const int* __restrict__ offsets,
                                              const int* __restrict__ rtok,
                                              f16* __restrict__ Hx)
{
    const int e = blockIdx.z;
    const int cnt = counts[e];
    const int mt = blockIdx.y * 64;
    if (mt >= cnt) return;
    const int off = offsets[e];
    const int n0 = blockIdx.x * 128;
    const f16* W = W1t + (size_t)e * MD * HD;

    __shared__ alignas(16) f16 As[2][64 * 32];
    __shared__ alignas(16) f16 Bs[2][128 * 32];
    GEMM_PREAMBLE

    int rm = mt + wave * 16 + sr;
    int s0 = off + (rm < cnt ? rm : cnt - 1);
    const f16* gA = Xh + (size_t)rtok[s0] * HD + sc;
    const f16* gB0 = W + (size_t)(n0 + wave * 32 + sr) * HD + sc;
    const f16* gB1 = gB0 + 16 * HD;

    f32x4 acc[2][4] = {};
    GEMM_STAGE(0, 0)
    int par = 0;
    for (int kt = 0; kt < HD; kt += 32) {
        __syncthreads();
        if (kt + 32 < HD) { int np = par ^ 1; GEMM_STAGE(np, kt + 32) }
        GEMM_MFMA(par)
        par ^= 1;
    }
    #pragma unroll
    for (int i = 0; i < 2; ++i)
        #pragma unroll
        for (int j = 0; j < 4; ++j)
            #pragma unroll
            for (int r = 0; r < 4; ++r) {
                int m_in = mt + wm + i * 16 + q * 4 + r;
                if (m_in < cnt) {
                    int n = n0 + wn + j * 16 + fr;
                    float v = acc[i][j][r];
                    Hx[(size_t)(off + m_in) * MD + n] = (f16)(v / (1.f + expf(-v)));
                }
            }
}

// expert GEMM2: Out[t] += w * (Hx @ W2[e]). K=512 N=1024, atomic scatter.
__global__ __launch_bounds__(256) void g_exp2(const f16* __restrict__ Hx,
                                              const f16* __restrict__ W2t, // [E][H][M]
                                              const int* __restrict__ counts,
                                              const int* __restrict__ offsets,
                                              const int* __restrict__ rtok,
                                              const float* __restrict__ rw,
                                              float* __restrict__ Out)
{
    const int e = blockIdx.z;
    const int cnt = counts[e];
    const int mt = blockIdx.y * 64;
    if (mt >= cnt) return;
    const int off = offsets[e];
    const int n0 = blockIdx.x * 128;
    const f16* W = W2t + (size_t)e * HD * MD;

    __shared__ alignas(16) f16 As[2][64 * 32];
    __shared__ alignas(16) f16 Bs[2][128 * 32];
    GEMM_PREAMBLE

    // A rows are packed slots; Hx pad rows make OOB reads safe (masked at C).
    const f16* gA = Hx + (size_t)(off + mt + wave * 16 + sr) * MD + sc;
    const f16* gB0 = W + (size_t)(n0 + wave * 32 + sr) * MD + sc;
    const f16* gB1 = gB0 + 16 * MD;

    f32x4 acc[2][4] = {};
    GEMM_STAGE(0, 0)
    int par = 0;
    for (int kt = 0; kt < MD; kt += 32) {
        __syncthreads();
        if (kt + 32 < MD) { int np = par ^ 1; GEMM_STAGE(np, kt + 32) }
        GEMM_MFMA(par)
        par ^= 1;
    }
    #pragma unroll
    for (int i = 0; i < 2; ++i)
        #pragma unroll
        for (int r = 0; r < 4; ++r) {
            int m_in = mt + wm + i * 16 + q * 4 + r;
            if (m_in < cnt) {
                int slot = off + m_in;
                int t = rtok[slot];
                float w = rw[slot];
                float* orow = Out + (size_t)t * HD + n0 + wn + fr;
                #pragma unroll
                for (int j = 0; j < 4; ++j)
                    atomicAdd(&orow[j * 16], w * acc[i][j][r]);
            }
        }
}

// ------------------------------------------------------------------
extern "C" void kernel_launch(void* const* d_in, const int* in_sizes, int n_in,
                              void* d_out, int out_size, void* d_ws, size_t ws_size,
                              hipStream_t stream)
{
    (void)in_sizes; (void)n_in; (void)out_size; (void)ws_size;
    const float* X   = (const float*)d_in[0];
    const float* Ws1 = (const float*)d_in[1];
    const float* Ws2 = (const float*)d_in[2];
    const float* Wg  = (const float*)d_in[3];
    const float* W1  = (const float*)d_in[4];
    const float* W2  = (const float*)d_in[5];
    float* out = (float*)d_out;
    float* logits = out + (size_t)NT * HD;

    char* ws = (char*)d_ws;
    f16*   h1       = (f16*)(ws + O_H1);
    f16*   hx       = (f16*)(ws + O_HX);
    int*   topk_idx = (int*)(ws + O_TOPKI);
    float* topk_w   = (float*)(ws + O_TOPKW);
    int*   counts   = (int*)(ws + O_COUNTS);
    int*   cursors  = (int*)(ws + O_CURSORS);
    int*   offsets  = (int*)(ws + O_OFFSETS);
    int*   rtok     = (int*)(ws + O_RTOK);
    float* rwt      = (float*)(ws + O_RW);
    f16*   xh       = (f16*)(ws + O_XH);
    f16*   w1t      = (f16*)(ws + O_W1T);
    f16*   w2t      = (f16*)(ws + O_W2T);
    f16*   ws1t     = (f16*)(ws + O_WS1T);
    f16*   ws2t     = (f16*)(ws + O_WS2T);

    hipMemsetAsync(counts, 0, 512, stream);   // counts + cursors

    k_router<<<NT / 4, 256, 0, stream>>>(X, Wg, logits);
    k_topk<<<NT, 64, 0, stream>>>(logits, topk_idx, topk_w, counts);
    k_scan<<<1, 64, 0, stream>>>(counts, offsets);
    k_route<<<NT * TOPK / 256, 256, 0, stream>>>(topk_idx, topk_w, offsets, cursors, rtok, rwt);

    // conversion pre-pass
    k_cvt_x<<<NT * HD / 1024, 256, 0, stream>>>(X, xh);
    k_cvt_t<<<dim3(FF / 64, HD / 64, 1), 256, 0, stream>>>(Ws1, ws1t, HD, FF);
    k_cvt_t<<<dim3(HD / 64, FF / 64, 1), 256, 0, stream>>>(Ws2, ws2t, FF, HD);
    k_cvt_t<<<dim3(MD / 64, HD / 64, NE), 256, 0, stream>>>(W1, w1t, HD, MD);
    k_cvt_t<<<dim3(HD / 64, MD / 64, NE), 256, 0, stream>>>(W2, w2t, MD, HD);
    hipMemsetAsync(out, 0, (size_t)NT * HD * 4, stream);

    g_shared1<<<dim3(FF / 128, NT / 64), 256, 0, stream>>>(xh, ws1t, h1);
    g_shared2<<<dim3(HD / 128, NT / 64, 4), 256, 0, stream>>>(h1, ws2t, out);
    g_exp1<<<dim3(MD / 128, NT / 64, NE), 256, 0, stream>>>(xh, w1t, counts, offsets, rtok, hx);
    g_exp2<<<dim3(HD / 128, NT / 64, NE), 256, 0, stream>>>(hx, w2t, counts, offsets, rtok, rwt, out);
}